// Round 1
// baseline (2290.646 us; speedup 1.0000x reference)
//
#include <hip/hip_runtime.h>
#include <hip/hip_bf16.h>

#define D_MODEL 256
#define NHEAD 8
#define DH 32
#define NLAYERS 4
#define DFF 1024
#define PATCH 8
#define CC 2
#define DATA_DIM 128
#define PP 16
#define TT 64
#define BB 4
#define LL 1024
#define NEGV -1000000.0f

__device__ __forceinline__ bool my_isnan(float v) {
    unsigned u = __float_as_uint(v);
    return (u & 0x7fffffffu) > 0x7f800000u;
}

// ---------------------------------------------------------------------------
// Prep: frame_pad detection + temporal embedding MLP (1 -> 64 -> 128 -> 256)
// grid: B*T blocks, 256 threads
// ---------------------------------------------------------------------------
__global__ void prep_frame_kernel(const float* __restrict__ img,
                                  const float* __restrict__ acq,
                                  const float* __restrict__ t_w1, const float* __restrict__ t_b1,
                                  const float* __restrict__ t_w2, const float* __restrict__ t_b2,
                                  const float* __restrict__ t_w3, const float* __restrict__ t_b3,
                                  float* __restrict__ temb, int* __restrict__ framepad) {
    int f = blockIdx.x;             // b*T + t
    int tid = threadIdx.x;
    __shared__ float h1[64];
    __shared__ float h2[128];
    __shared__ int sAll;
    if (tid == 0) sAll = 1;
    __syncthreads();
    const float* fr = img + (size_t)f * (CC * 32 * 32);
    bool allpad = true;
    #pragma unroll
    for (int i = 0; i < 8; ++i) {
        float v = fr[tid + i * 256];
        allpad = allpad && (v == -9999.0f);
    }
    if (!allpad) sAll = 0;
    __syncthreads();
    if (tid == 0) framepad[f] = sAll;

    float t_in = acq[f];
    if (my_isnan(t_in)) t_in = 0.0f;
    if (tid < 64) h1[tid] = fmaxf(t_w1[tid] * t_in + t_b1[tid], 0.0f);
    __syncthreads();
    if (tid < 128) {
        float a = t_b2[tid];
        #pragma unroll 8
        for (int j = 0; j < 64; ++j) a += t_w2[tid * 64 + j] * h1[j];
        h2[tid] = fmaxf(a, 0.0f);
    }
    __syncthreads();
    {
        float a = t_b3[tid];
        #pragma unroll 8
        for (int j = 0; j < 128; ++j) a += t_w3[tid * 128 + j] * h2[j];
        temb[(size_t)f * D_MODEL + tid] = a;
    }
}

// ---------------------------------------------------------------------------
// Embed: patchify + NaN replace + clip + linear embed + pos + temb + pad_embed
// grid: B*T*P blocks (4096), 256 threads (one per output dim)
// ---------------------------------------------------------------------------
__global__ void embed_kernel(const float* __restrict__ img,
                             const float* __restrict__ nan_token,
                             const float* __restrict__ pad_embed,
                             const float* __restrict__ emb_w, const float* __restrict__ emb_b,
                             const float* __restrict__ spatial_pos,
                             const float* __restrict__ temb,
                             const int* __restrict__ framepad,
                             float* __restrict__ z,
                             int* __restrict__ masked_rows, int* __restrict__ seq_pad) {
    int token = blockIdx.x;
    int b = token / (TT * PP);
    int rem = token % (TT * PP);
    int t = rem / PP;
    int p = rem % PP;
    int tid = threadIdx.x;
    __shared__ float xs[DATA_DIM];
    __shared__ int anyvalid;
    if (tid == 0) anyvalid = 0;
    __syncthreads();
    if (tid < DATA_DIM) {
        int c = tid >> 6;
        int pr = (tid >> 3) & 7;
        int pc = tid & 7;
        int hh = (p >> 2) * 8 + pr;
        int ww = (p & 3) * 8 + pc;
        float v = img[(((size_t)(b * TT + t) * CC + c) * 32 + hh) * 32 + ww];
        if (my_isnan(v)) {
            v = fminf(fmaxf(nan_token[c], -10.0f), 10.0f);
        } else {
            anyvalid = 1;
        }
        v = fminf(fmaxf(v, -10.0f), 10.0f);
        xs[tid] = v;
    }
    __syncthreads();
    int fp = framepad[b * TT + t];
    int l = t * PP + p;
    float zv;
    if (fp) {
        zv = pad_embed[tid];
    } else {
        float acc = emb_b[tid] + spatial_pos[p * D_MODEL + tid]
                  + temb[(size_t)(b * TT + t) * D_MODEL + tid];
        #pragma unroll 8
        for (int j = 0; j < DATA_DIM; ++j) acc += xs[j] * emb_w[tid * DATA_DIM + j];
        zv = acc;
    }
    z[((size_t)(b * LL + l)) * D_MODEL + tid] = zv;
    if (tid == 0) {
        int sn = (anyvalid == 0) ? 1 : 0;
        masked_rows[b * LL + l] = sn | fp;
        seq_pad[b * LL + l] = fp;
    }
}

// ---------------------------------------------------------------------------
// Generic GEMM: Y[M,N] = act(X[M,K] @ W[N,K]^T + bias[N])
// 64x64 tile, 256 threads, 4x4 micro-tile, K-step 16. Requires M%64==0 or
// M==64 exactly per grid; N%64==0; K%16==0.
// ---------------------------------------------------------------------------
template <int ACT>
__global__ void gemm_bias_kernel(const float* __restrict__ X, const float* __restrict__ W,
                                 const float* __restrict__ bias, float* __restrict__ Y,
                                 int M, int N, int K) {
    __shared__ float Xs[64][17];
    __shared__ float Ws[64][17];
    int tid = threadIdx.x;
    int tx = tid & 15;
    int ty = tid >> 4;
    int row0 = blockIdx.y * 64;
    int col0 = blockIdx.x * 64;
    float acc[4][4] = {};
    int lr = tid >> 2;            // 0..63
    int lk = (tid & 3) * 4;       // 0,4,8,12
    for (int k0 = 0; k0 < K; k0 += 16) {
        float4 xv = *(const float4*)&X[(size_t)(row0 + lr) * K + k0 + lk];
        float4 wv = *(const float4*)&W[(size_t)(col0 + lr) * K + k0 + lk];
        Xs[lr][lk + 0] = xv.x; Xs[lr][lk + 1] = xv.y; Xs[lr][lk + 2] = xv.z; Xs[lr][lk + 3] = xv.w;
        Ws[lr][lk + 0] = wv.x; Ws[lr][lk + 1] = wv.y; Ws[lr][lk + 2] = wv.z; Ws[lr][lk + 3] = wv.w;
        __syncthreads();
        #pragma unroll
        for (int kk = 0; kk < 16; ++kk) {
            float a[4], bb[4];
            #pragma unroll
            for (int i = 0; i < 4; ++i) a[i] = Xs[ty * 4 + i][kk];
            #pragma unroll
            for (int j = 0; j < 4; ++j) bb[j] = Ws[tx * 4 + j][kk];
            #pragma unroll
            for (int i = 0; i < 4; ++i)
                #pragma unroll
                for (int j = 0; j < 4; ++j) acc[i][j] += a[i] * bb[j];
        }
        __syncthreads();
    }
    #pragma unroll
    for (int i = 0; i < 4; ++i) {
        int row = row0 + ty * 4 + i;
        #pragma unroll
        for (int j = 0; j < 4; ++j) {
            int col = col0 + tx * 4 + j;
            float v = acc[i][j] + bias[col];
            if (ACT == 1) v = fmaxf(v, 0.0f);
            Y[(size_t)row * N + col] = v;
        }
    }
}

// ---------------------------------------------------------------------------
// Attention: one block per (b, h, q-tile of 8 rows). 256 threads.
// Exact softmax; mask per reference semantics.
// qkv rows: [q(256) | k(256) | v(256)] = 768 floats per token.
// ---------------------------------------------------------------------------
#define QT 8
__global__ void attn_kernel(const float* __restrict__ qkv,
                            const int* __restrict__ masked_rows,
                            const int* __restrict__ seq_pad,
                            float* __restrict__ out) {
    __shared__ float P_[QT][LL];        // 32 KB
    __shared__ float KV[64][33];        // 8.4 KB staging for K then V chunks
    __shared__ float Qt[QT][33];        // padded
    __shared__ float red[256];
    __shared__ float rowsum[QT];

    const int nq = LL / QT;             // 128
    int bid = blockIdx.x;
    int b = bid / (NHEAD * nq);
    int rem = bid % (NHEAD * nq);
    int h = rem / nq;
    int qt = rem % nq;
    int l0 = qt * QT;
    int tid = threadIdx.x;
    int q = tid & (QT - 1);             // 0..7
    int kg = tid >> 3;                  // 0..31

    // load Q tile
    {
        int qq = tid >> 5, d = tid & 31;
        Qt[qq][d] = qkv[((size_t)(b * LL + l0 + qq)) * 768 + h * DH + d];
    }
    __syncthreads();

    const float scale = 0.1767766952966369f;   // 1/sqrt(32)
    int qg = l0 + q;
    int mq = masked_rows[b * LL + qg];

    float s[32];
    for (int cc = 0; cc < 16; ++cc) {
        {   // stage K rows [cc*64, cc*64+64)
            int e = tid * 8;
            int r = e >> 5, d = e & 31;
            const float* src = &qkv[((size_t)(b * LL + cc * 64 + r)) * 768 + 256 + h * DH + d];
            float4 v0 = *(const float4*)(src);
            float4 v1 = *(const float4*)(src + 4);
            KV[r][d + 0] = v0.x; KV[r][d + 1] = v0.y; KV[r][d + 2] = v0.z; KV[r][d + 3] = v0.w;
            KV[r][d + 4] = v1.x; KV[r][d + 5] = v1.y; KV[r][d + 6] = v1.z; KV[r][d + 7] = v1.w;
        }
        __syncthreads();
        #pragma unroll
        for (int ii = 0; ii < 2; ++ii) {
            int i = cc * 2 + ii;
            int rloc = kg + 32 * ii;
            int k = cc * 64 + rloc;
            float acc = 0.0f;
            #pragma unroll
            for (int d = 0; d < DH; ++d) acc += Qt[q][d] * KV[rloc][d];
            float m = 0.0f;
            if (mq && (qg != k)) m += NEGV;
            if (seq_pad[b * LL + k]) m += NEGV;
            s[i] = acc * scale + m;
        }
        __syncthreads();
    }

    // softmax over k (32 regs per thread x 32 k-groups per q-row)
    float lm = -3.4e38f;
    #pragma unroll
    for (int i = 0; i < 32; ++i) lm = fmaxf(lm, s[i]);
    red[tid] = lm;
    __syncthreads();
    for (int st = 16; st > 0; st >>= 1) {
        if (tid < QT * st) red[tid] = fmaxf(red[tid], red[tid + QT * st]);
        __syncthreads();
    }
    float rmax = red[q];
    __syncthreads();
    float ls = 0.0f;
    #pragma unroll
    for (int i = 0; i < 32; ++i) {
        float pv = expf(s[i] - rmax);
        s[i] = pv;
        ls += pv;
    }
    red[tid] = ls;
    __syncthreads();
    for (int st = 16; st > 0; st >>= 1) {
        if (tid < QT * st) red[tid] += red[tid + QT * st];
        __syncthreads();
    }
    if (tid < QT) rowsum[tid] = red[tid];
    __syncthreads();

    #pragma unroll
    for (int i = 0; i < 32; ++i) P_[q][kg + 32 * i] = s[i];
    __syncthreads();

    // O = P @ V : one (q,d) per thread
    int qq = tid >> 5, d = tid & 31;
    float acc = 0.0f;
    for (int cc = 0; cc < 16; ++cc) {
        {   // stage V rows
            int e = tid * 8;
            int r = e >> 5, dd = e & 31;
            const float* src = &qkv[((size_t)(b * LL + cc * 64 + r)) * 768 + 512 + h * DH + dd];
            float4 v0 = *(const float4*)(src);
            float4 v1 = *(const float4*)(src + 4);
            KV[r][dd + 0] = v0.x; KV[r][dd + 1] = v0.y; KV[r][dd + 2] = v0.z; KV[r][dd + 3] = v0.w;
            KV[r][dd + 4] = v1.x; KV[r][dd + 5] = v1.y; KV[r][dd + 6] = v1.z; KV[r][dd + 7] = v1.w;
        }
        __syncthreads();
        #pragma unroll 16
        for (int r2 = 0; r2 < 64; ++r2) acc += P_[qq][cc * 64 + r2] * KV[r2][d];
        __syncthreads();
    }
    out[((size_t)(b * LL + l0 + qq)) * D_MODEL + h * DH + d] = acc / rowsum[qq];
}

// ---------------------------------------------------------------------------
// Residual add + LayerNorm over D=256. One block (256 threads) per row.
// z <- LN(z + o) * w + b
// ---------------------------------------------------------------------------
__global__ void add_ln_kernel(float* __restrict__ z, const float* __restrict__ o,
                              const float* __restrict__ w, const float* __restrict__ b) {
    int row = blockIdx.x;
    int tid = threadIdx.x;
    __shared__ float red[256];
    size_t idx = (size_t)row * D_MODEL + tid;
    float x = z[idx] + o[idx];
    red[tid] = x;
    __syncthreads();
    for (int st = 128; st > 0; st >>= 1) {
        if (tid < st) red[tid] += red[tid + st];
        __syncthreads();
    }
    float mean = red[0] * (1.0f / D_MODEL);
    __syncthreads();
    float dx = x - mean;
    red[tid] = dx * dx;
    __syncthreads();
    for (int st = 128; st > 0; st >>= 1) {
        if (tid < st) red[tid] += red[tid + st];
        __syncthreads();
    }
    float var = red[0] * (1.0f / D_MODEL);
    float inv = 1.0f / sqrtf(var + 1e-5f);
    z[idx] = dx * inv * w[tid] + b[tid];
}

// ---------------------------------------------------------------------------
// Gather last-frame rows of z into compact (B*P, D) buffer
// ---------------------------------------------------------------------------
__global__ void gather_last_kernel(const float* __restrict__ z, float* __restrict__ zlast) {
    int row = blockIdx.x;       // 0..63  (b*16 + p)
    int tid = threadIdx.x;
    int b = row >> 4;
    int p = row & 15;
    int l = (TT - 1) * PP + p;
    zlast[(size_t)row * D_MODEL + tid] = z[((size_t)(b * LL + l)) * D_MODEL + tid];
}

// ---------------------------------------------------------------------------
// Clip + unpatch scatter: pre (B*P, 128) -> out (B, C, 32, 32) flat
// ---------------------------------------------------------------------------
__global__ void scatter_head_kernel(const float* __restrict__ pre, float* __restrict__ out,
                                    float lo, float hi) {
    int e = blockIdx.x * 256 + threadIdx.x;   // 0..8191
    int ww = e & 31;
    int hh = (e >> 5) & 31;
    int c = (e >> 10) & 1;
    int b = e >> 11;
    int p = (hh >> 3) * 4 + (ww >> 3);
    int dd = c * 64 + (hh & 7) * 8 + (ww & 7);
    float v = pre[((size_t)(b * PP + p)) * DATA_DIM + dd];
    out[e] = fminf(fmaxf(v, lo), hi);
}

// ---------------------------------------------------------------------------
extern "C" void kernel_launch(void* const* d_in, const int* in_sizes, int n_in,
                              void* d_out, int out_size, void* d_ws, size_t ws_size,
                              hipStream_t stream) {
    const float* img        = (const float*)d_in[0];
    const float* acq        = (const float*)d_in[1];
    const float* nan_token  = (const float*)d_in[2];
    const float* pad_embed  = (const float*)d_in[3];
    const float* emb_w      = (const float*)d_in[4];
    const float* emb_b      = (const float*)d_in[5];
    const float* spatial    = (const float*)d_in[6];
    const float* t_w1       = (const float*)d_in[7];
    const float* t_b1       = (const float*)d_in[8];
    const float* t_w2       = (const float*)d_in[9];
    const float* t_b2       = (const float*)d_in[10];
    const float* t_w3       = (const float*)d_in[11];
    const float* t_b3       = (const float*)d_in[12];
    const float* in_proj_w  = (const float*)d_in[13];
    const float* in_proj_b  = (const float*)d_in[14];
    const float* out_proj_w = (const float*)d_in[15];
    const float* out_proj_b = (const float*)d_in[16];
    const float* lin1_w     = (const float*)d_in[17];
    const float* lin1_b     = (const float*)d_in[18];
    const float* lin2_w     = (const float*)d_in[19];
    const float* lin2_b     = (const float*)d_in[20];
    const float* norm1_w    = (const float*)d_in[21];
    const float* norm1_b    = (const float*)d_in[22];
    const float* norm2_w    = (const float*)d_in[23];
    const float* norm2_b    = (const float*)d_in[24];
    const float* mean_w1    = (const float*)d_in[25];
    const float* mean_b1    = (const float*)d_in[26];
    const float* mean_w2    = (const float*)d_in[27];
    const float* mean_b2    = (const float*)d_in[28];
    const float* lv_w1      = (const float*)d_in[29];
    const float* lv_b1      = (const float*)d_in[30];
    const float* lv_w2      = (const float*)d_in[31];
    const float* lv_b2      = (const float*)d_in[32];

    const int M = BB * LL;               // 4096 tokens

    float* ws = (float*)d_ws;
    float* z       = ws;                         // 4096*256   = 1,048,576
    float* bufA    = z + (size_t)M * D_MODEL;    // 4096*1024  = 4,194,304 (qkv / ff1 / o)
    float* bufB    = bufA + (size_t)M * DFF;     // 4096*256   = 1,048,576 (attn / ff2)
    float* temb    = bufB + (size_t)M * D_MODEL; // 256*256    = 65,536
    float* zlast   = temb + BB * TT * D_MODEL;   // 64*256     = 16,384
    float* hhead   = zlast + 64 * D_MODEL;       // 64*1024    = 65,536
    float* prehead = hhead + 64 * DFF;           // 64*128     = 8,192
    int* framepad  = (int*)(prehead + 64 * DATA_DIM); // 256
    int* masked    = framepad + BB * TT;              // 4096
    int* seqpad    = masked + M;                      // 4096

    float* outF = (float*)d_out;

    // --- prep + embed ---
    prep_frame_kernel<<<BB * TT, 256, 0, stream>>>(img, acq, t_w1, t_b1, t_w2, t_b2,
                                                   t_w3, t_b3, temb, framepad);
    embed_kernel<<<BB * TT * PP, 256, 0, stream>>>(img, nan_token, pad_embed, emb_w, emb_b,
                                                   spatial, temb, framepad, z, masked, seqpad);

    // --- transformer layers ---
    for (int l = 0; l < NLAYERS; ++l) {
        // qkv = z @ in_proj_w^T + b   (4096 x 768)
        gemm_bias_kernel<0><<<dim3(768 / 64, M / 64), 256, 0, stream>>>(
            z, in_proj_w + (size_t)l * 768 * D_MODEL, in_proj_b + (size_t)l * 768,
            bufA, M, 768, D_MODEL);
        // attention -> bufB (4096 x 256)
        attn_kernel<<<BB * NHEAD * (LL / QT), 256, 0, stream>>>(bufA, masked, seqpad, bufB);
        // o = attn @ out_proj^T + b -> bufA (reuse)
        gemm_bias_kernel<0><<<dim3(D_MODEL / 64, M / 64), 256, 0, stream>>>(
            bufB, out_proj_w + (size_t)l * D_MODEL * D_MODEL, out_proj_b + (size_t)l * D_MODEL,
            bufA, M, D_MODEL, D_MODEL);
        // z = LN(z + o)
        add_ln_kernel<<<M, 256, 0, stream>>>(z, bufA, norm1_w + l * D_MODEL, norm1_b + l * D_MODEL);
        // ff1 = relu(z @ lin1^T + b)  (4096 x 1024)
        gemm_bias_kernel<1><<<dim3(DFF / 64, M / 64), 256, 0, stream>>>(
            z, lin1_w + (size_t)l * DFF * D_MODEL, lin1_b + (size_t)l * DFF,
            bufA, M, DFF, D_MODEL);
        // ff2 = ff1 @ lin2^T + b      (4096 x 256)
        gemm_bias_kernel<0><<<dim3(D_MODEL / 64, M / 64), 256, 0, stream>>>(
            bufA, lin2_w + (size_t)l * D_MODEL * DFF, lin2_b + (size_t)l * D_MODEL,
            bufB, M, D_MODEL, DFF);
        // z = LN(z + ff2)
        add_ln_kernel<<<M, 256, 0, stream>>>(z, bufB, norm2_w + l * D_MODEL, norm2_b + l * D_MODEL);
    }

    // --- heads on last frame only (64 rows) ---
    gather_last_kernel<<<64, 256, 0, stream>>>(z, zlast);

    // mean head
    gemm_bias_kernel<1><<<dim3(DFF / 64, 1), 256, 0, stream>>>(
        zlast, mean_w1, mean_b1, hhead, 64, DFF, D_MODEL);
    gemm_bias_kernel<0><<<dim3(DATA_DIM / 64, 1), 256, 0, stream>>>(
        hhead, mean_w2, mean_b2, prehead, 64, DATA_DIM, DFF);
    scatter_head_kernel<<<32, 256, 0, stream>>>(prehead, outF, -10.0f, 10.0f);

    // logvar head
    gemm_bias_kernel<1><<<dim3(DFF / 64, 1), 256, 0, stream>>>(
        zlast, lv_w1, lv_b1, hhead, 64, DFF, D_MODEL);
    gemm_bias_kernel<0><<<dim3(DATA_DIM / 64, 1), 256, 0, stream>>>(
        hhead, lv_w2, lv_b2, prehead, 64, DATA_DIM, DFF);
    scatter_head_kernel<<<32, 256, 0, stream>>>(prehead, outF + 8192, -10.0f, 5.0f);
}

// Round 2
// 822.546 us; speedup vs baseline: 2.7848x; 2.7848x over previous
//
#include <hip/hip_runtime.h>
#include <hip/hip_bf16.h>

#define D_MODEL 256
#define NHEAD 8
#define DH 32
#define NLAYERS 4
#define DFF 1024
#define CC 2
#define DATA_DIM 128
#define PP 16
#define TT 64
#define BB 4
#define LL 1024
#define NEGV -1000000.0f

typedef __bf16 bf16_t;
typedef __bf16 bf16x8 __attribute__((ext_vector_type(8)));
typedef __bf16 bf16x4 __attribute__((ext_vector_type(4)));
typedef float v4f __attribute__((ext_vector_type(4)));

__device__ __forceinline__ bool my_isnan(float v) {
    unsigned u = __float_as_uint(v);
    return (u & 0x7fffffffu) > 0x7f800000u;
}

// ---------------------------------------------------------------------------
// fp32 -> bf16 conversion (weights), vectorized x4
// ---------------------------------------------------------------------------
__global__ void f2b_kernel(const float* __restrict__ src, bf16_t* __restrict__ dst, int n) {
    int i = (blockIdx.x * 256 + threadIdx.x) * 4;
    if (i < n) {
        float4 v = *(const float4*)(src + i);
        bf16x4 o = {(bf16_t)v.x, (bf16_t)v.y, (bf16_t)v.z, (bf16_t)v.w};
        *(bf16x4*)(dst + i) = o;
    }
}

// ---------------------------------------------------------------------------
// Prep: frame_pad detection + temporal embedding MLP (1 -> 64 -> 128 -> 256)
// ---------------------------------------------------------------------------
__global__ void prep_frame_kernel(const float* __restrict__ img,
                                  const float* __restrict__ acq,
                                  const float* __restrict__ t_w1, const float* __restrict__ t_b1,
                                  const float* __restrict__ t_w2, const float* __restrict__ t_b2,
                                  const float* __restrict__ t_w3, const float* __restrict__ t_b3,
                                  float* __restrict__ temb, int* __restrict__ framepad) {
    int f = blockIdx.x;
    int tid = threadIdx.x;
    __shared__ float h1[64];
    __shared__ float h2[128];
    __shared__ int sAll;
    if (tid == 0) sAll = 1;
    __syncthreads();
    const float* fr = img + (size_t)f * (CC * 32 * 32);
    bool allpad = true;
    #pragma unroll
    for (int i = 0; i < 8; ++i) {
        float v = fr[tid + i * 256];
        allpad = allpad && (v == -9999.0f);
    }
    if (!allpad) sAll = 0;
    __syncthreads();
    if (tid == 0) framepad[f] = sAll;

    float t_in = acq[f];
    if (my_isnan(t_in)) t_in = 0.0f;
    if (tid < 64) h1[tid] = fmaxf(t_w1[tid] * t_in + t_b1[tid], 0.0f);
    __syncthreads();
    if (tid < 128) {
        float a = t_b2[tid];
        #pragma unroll 8
        for (int j = 0; j < 64; ++j) a += t_w2[tid * 64 + j] * h1[j];
        h2[tid] = fmaxf(a, 0.0f);
    }
    __syncthreads();
    {
        float a = t_b3[tid];
        #pragma unroll 8
        for (int j = 0; j < 128; ++j) a += t_w3[tid * 128 + j] * h2[j];
        temb[(size_t)f * D_MODEL + tid] = a;
    }
}

// ---------------------------------------------------------------------------
// Embed: patchify + NaN/clip + linear embed + pos + temb + pad_embed
// writes z (fp32), zb (bf16), masked_rows, kmaskf
// ---------------------------------------------------------------------------
__global__ void embed_kernel(const float* __restrict__ img,
                             const float* __restrict__ nan_token,
                             const float* __restrict__ pad_embed,
                             const float* __restrict__ emb_w, const float* __restrict__ emb_b,
                             const float* __restrict__ spatial_pos,
                             const float* __restrict__ temb,
                             const int* __restrict__ framepad,
                             float* __restrict__ z, bf16_t* __restrict__ zb,
                             int* __restrict__ masked_rows, float* __restrict__ kmaskf) {
    int token = blockIdx.x;
    int b = token / (TT * PP);
    int rem = token % (TT * PP);
    int t = rem / PP;
    int p = rem % PP;
    int tid = threadIdx.x;
    __shared__ float xs[DATA_DIM];
    __shared__ int anyvalid;
    if (tid == 0) anyvalid = 0;
    __syncthreads();
    if (tid < DATA_DIM) {
        int c = tid >> 6;
        int pr = (tid >> 3) & 7;
        int pc = tid & 7;
        int hh = (p >> 2) * 8 + pr;
        int ww = (p & 3) * 8 + pc;
        float v = img[(((size_t)(b * TT + t) * CC + c) * 32 + hh) * 32 + ww];
        if (my_isnan(v)) {
            v = fminf(fmaxf(nan_token[c], -10.0f), 10.0f);
        } else {
            anyvalid = 1;
        }
        v = fminf(fmaxf(v, -10.0f), 10.0f);
        xs[tid] = v;
    }
    __syncthreads();
    int fp = framepad[b * TT + t];
    int l = t * PP + p;
    float zv;
    if (fp) {
        zv = pad_embed[tid];
    } else {
        float acc = emb_b[tid] + spatial_pos[p * D_MODEL + tid]
                  + temb[(size_t)(b * TT + t) * D_MODEL + tid];
        #pragma unroll 8
        for (int j = 0; j < DATA_DIM; ++j) acc += xs[j] * emb_w[tid * DATA_DIM + j];
        zv = acc;
    }
    size_t idx = ((size_t)(b * LL + l)) * D_MODEL + tid;
    z[idx] = zv;
    zb[idx] = (bf16_t)zv;
    if (tid == 0) {
        int sn = (anyvalid == 0) ? 1 : 0;
        masked_rows[b * LL + l] = sn | fp;
        kmaskf[b * LL + l] = fp ? NEGV : 0.0f;
    }
}

// ---------------------------------------------------------------------------
// MFMA GEMM: Y[M,N] = act(Xbf16[M,K] @ Wbf16[N,K]^T + bias[N])
// BM=128, BN=64, BK=32, 256 threads (4 waves), wave = 32 rows x 64 cols.
// MODE 0: fp32 out; 1: bf16 out; 2: qkv split (Q/K row-major bf16, V transposed)
// ---------------------------------------------------------------------------
template <int MODE, int RELU>
__global__ __launch_bounds__(256) void gemm_mfma(
    const bf16_t* __restrict__ X, const bf16_t* __restrict__ W,
    const float* __restrict__ bias, void* __restrict__ Yv,
    bf16_t* __restrict__ Qb, bf16_t* __restrict__ Kb, bf16_t* __restrict__ Vt,
    int M, int N, int K) {
    __shared__ __align__(16) bf16_t Xs[128 * 32];
    __shared__ __align__(16) bf16_t Ws[64 * 32];
    int tid = threadIdx.x;
    int wave = tid >> 6, lane = tid & 63;
    int quad = lane >> 4, l16 = lane & 15;
    int m0 = blockIdx.y * 128, n0 = blockIdx.x * 64;

    v4f acc[2][4];
    #pragma unroll
    for (int i = 0; i < 2; ++i)
        #pragma unroll
        for (int j = 0; j < 4; ++j) acc[i][j] = (v4f){0.f, 0.f, 0.f, 0.f};

    int sr = tid >> 2, ss = tid & 3;
    for (int k0 = 0; k0 < K; k0 += 32) {
        uint4 a0 = *(const uint4*)(X + (size_t)(m0 + sr) * K + k0 + ss * 8);
        uint4 a1 = *(const uint4*)(X + (size_t)(m0 + 64 + sr) * K + k0 + ss * 8);
        uint4 b0 = *(const uint4*)(W + (size_t)(n0 + sr) * K + k0 + ss * 8);
        *(uint4*)(Xs + sr * 32 + ss * 8) = a0;
        *(uint4*)(Xs + (64 + sr) * 32 + ss * 8) = a1;
        *(uint4*)(Ws + sr * 32 + ss * 8) = b0;
        __syncthreads();
        bf16x8 af0 = *(const bf16x8*)(Xs + (wave * 32 + l16) * 32 + quad * 8);
        bf16x8 af1 = *(const bf16x8*)(Xs + (wave * 32 + 16 + l16) * 32 + quad * 8);
        #pragma unroll
        for (int nt = 0; nt < 4; ++nt) {
            bf16x8 bfr = *(const bf16x8*)(Ws + (nt * 16 + l16) * 32 + quad * 8);
            acc[0][nt] = __builtin_amdgcn_mfma_f32_16x16x32_bf16(af0, bfr, acc[0][nt], 0, 0, 0);
            acc[1][nt] = __builtin_amdgcn_mfma_f32_16x16x32_bf16(af1, bfr, acc[1][nt], 0, 0, 0);
        }
        __syncthreads();
    }

    #pragma unroll
    for (int mt = 0; mt < 2; ++mt) {
        #pragma unroll
        for (int nt = 0; nt < 4; ++nt) {
            int col = n0 + nt * 16 + l16;
            float bv = bias[col];
            #pragma unroll
            for (int reg = 0; reg < 4; ++reg) {
                int row = m0 + wave * 32 + mt * 16 + quad * 4 + reg;
                float v = acc[mt][nt][reg] + bv;
                if (RELU) v = fmaxf(v, 0.0f);
                if (MODE == 0) {
                    ((float*)Yv)[(size_t)row * N + col] = v;
                } else if (MODE == 1) {
                    ((bf16_t*)Yv)[(size_t)row * N + col] = (bf16_t)v;
                } else {
                    if (col < 256) {
                        Qb[(size_t)row * 256 + col] = (bf16_t)v;
                    } else if (col < 512) {
                        Kb[(size_t)row * 256 + (col - 256)] = (bf16_t)v;
                    } else {
                        int c = col - 512;
                        int h = c >> 5, d = c & 31;
                        int b = row >> 10, l = row & 1023;
                        Vt[(((size_t)(b * NHEAD + h)) * DH + d) * LL + l] = (bf16_t)v;
                    }
                }
            }
        }
    }
}

// ---------------------------------------------------------------------------
// Flash attention, bf16 MFMA. Block = (b, h, 64-row q-tile); wave = 16 q-rows.
// K chunk row-major LDS (stride 40), V pre-transposed global -> LDS (stride 72),
// P via padded LDS round-trip (stride 72). Online softmax in quad via shfl_xor.
// ---------------------------------------------------------------------------
__global__ __launch_bounds__(256) void attn_mfma(
    const bf16_t* __restrict__ Qb, const bf16_t* __restrict__ Kb,
    const bf16_t* __restrict__ Vt,
    const int* __restrict__ masked_rows, const float* __restrict__ kmaskf,
    bf16_t* __restrict__ Ob) {
    __shared__ __align__(16) bf16_t Ks[64 * 40];
    __shared__ __align__(16) bf16_t Vs[32 * 72];
    __shared__ __align__(16) bf16_t Ps[4 * 16 * 72];

    int tid = threadIdx.x;
    int wave = tid >> 6, lane = tid & 63;
    int quad = lane >> 4, l16 = lane & 15;
    int bid = blockIdx.x;
    int qt = bid & 15, h = (bid >> 4) & 7, b = bid >> 7;
    int q0 = qt * 64 + wave * 16;
    const float scale = 0.17677669529663687f;

    bf16x8 qf = *(const bf16x8*)(Qb + ((size_t)(b * LL) + q0 + l16) * 256 + h * DH + quad * 8);

    int mq[4];
    #pragma unroll
    for (int reg = 0; reg < 4; ++reg) mq[reg] = masked_rows[b * LL + q0 + quad * 4 + reg];

    float mrun[4], lrun[4];
    v4f oacc[2];
    #pragma unroll
    for (int reg = 0; reg < 4; ++reg) { mrun[reg] = -3.0e38f; lrun[reg] = 0.0f; }
    oacc[0] = (v4f){0.f, 0.f, 0.f, 0.f};
    oacc[1] = (v4f){0.f, 0.f, 0.f, 0.f};

    bf16_t* Pw = Ps + wave * 16 * 72;
    int kr = tid >> 2, ks = tid & 3;       // K staging: 64 rows x 4 segs
    int vd = tid >> 3, vs = tid & 7;       // V staging: 32 rows x 8 segs

    for (int c = 0; c < 16; ++c) {
        int k0 = c * 64;
        *(uint4*)(Ks + kr * 40 + ks * 8) =
            *(const uint4*)(Kb + ((size_t)(b * LL) + k0 + kr) * 256 + h * DH + ks * 8);
        *(uint4*)(Vs + vd * 72 + vs * 8) =
            *(const uint4*)(Vt + (((size_t)(b * NHEAD + h)) * DH + vd) * LL + k0 + vs * 8);
        __syncthreads();

        v4f sf[4];
        #pragma unroll
        for (int nt = 0; nt < 4; ++nt) {
            bf16x8 kf = *(const bf16x8*)(Ks + (nt * 16 + l16) * 40 + quad * 8);
            v4f zf = (v4f){0.f, 0.f, 0.f, 0.f};
            sf[nt] = __builtin_amdgcn_mfma_f32_16x16x32_bf16(qf, kf, zf, 0, 0, 0);
        }

        float sv[4][4];
        #pragma unroll
        for (int nt = 0; nt < 4; ++nt) {
            int kg = k0 + nt * 16 + l16;
            float km = kmaskf[b * LL + kg];
            #pragma unroll
            for (int reg = 0; reg < 4; ++reg) {
                float v = sf[nt][reg] * scale + km;
                if (mq[reg] && (q0 + quad * 4 + reg != kg)) v += NEGV;
                sv[nt][reg] = v;
            }
        }

        float tm[4];
        #pragma unroll
        for (int reg = 0; reg < 4; ++reg) {
            float m = sv[0][reg];
            m = fmaxf(m, sv[1][reg]); m = fmaxf(m, sv[2][reg]); m = fmaxf(m, sv[3][reg]);
            tm[reg] = m;
        }
        #pragma unroll
        for (int off = 1; off < 16; off <<= 1)
            #pragma unroll
            for (int reg = 0; reg < 4; ++reg) tm[reg] = fmaxf(tm[reg], __shfl_xor(tm[reg], off));

        float alpha[4], psum[4];
        #pragma unroll
        for (int reg = 0; reg < 4; ++reg) {
            float mnew = fmaxf(mrun[reg], tm[reg]);
            alpha[reg] = __expf(mrun[reg] - mnew);
            mrun[reg] = mnew;
            float ps = 0.0f;
            #pragma unroll
            for (int nt = 0; nt < 4; ++nt) {
                float p = __expf(sv[nt][reg] - mnew);
                sv[nt][reg] = p;
                ps += p;
            }
            psum[reg] = ps;
        }
        #pragma unroll
        for (int off = 1; off < 16; off <<= 1)
            #pragma unroll
            for (int reg = 0; reg < 4; ++reg) psum[reg] += __shfl_xor(psum[reg], off);
        #pragma unroll
        for (int reg = 0; reg < 4; ++reg) {
            lrun[reg] = lrun[reg] * alpha[reg] + psum[reg];
            oacc[0][reg] *= alpha[reg];
            oacc[1][reg] *= alpha[reg];
        }

        #pragma unroll
        for (int nt = 0; nt < 4; ++nt)
            #pragma unroll
            for (int reg = 0; reg < 4; ++reg)
                Pw[(quad * 4 + reg) * 72 + nt * 16 + l16] = (bf16_t)sv[nt][reg];

        #pragma unroll
        for (int kt = 0; kt < 2; ++kt) {
            bf16x8 pf = *(const bf16x8*)(Pw + l16 * 72 + kt * 32 + quad * 8);
            #pragma unroll
            for (int nt2 = 0; nt2 < 2; ++nt2) {
                bf16x8 vf = *(const bf16x8*)(Vs + (nt2 * 16 + l16) * 72 + kt * 32 + quad * 8);
                oacc[nt2] = __builtin_amdgcn_mfma_f32_16x16x32_bf16(pf, vf, oacc[nt2], 0, 0, 0);
            }
        }
        __syncthreads();
    }

    #pragma unroll
    for (int nt2 = 0; nt2 < 2; ++nt2)
        #pragma unroll
        for (int reg = 0; reg < 4; ++reg) {
            size_t row = (size_t)(b * LL) + q0 + quad * 4 + reg;
            Ob[row * 256 + h * DH + nt2 * 16 + l16] = (bf16_t)(oacc[nt2][reg] / lrun[reg]);
        }
}

// ---------------------------------------------------------------------------
// Residual add + LayerNorm, wave-per-row (no barriers). Writes z fp32 + zb bf16.
// ---------------------------------------------------------------------------
__global__ __launch_bounds__(256) void add_ln_kernel(
    float* __restrict__ z, const float* __restrict__ o,
    const float* __restrict__ w, const float* __restrict__ b,
    bf16_t* __restrict__ zb) {
    int wave = threadIdx.x >> 6, lane = threadIdx.x & 63;
    int row = blockIdx.x * 4 + wave;
    float4 x = ((const float4*)(z + (size_t)row * D_MODEL))[lane];
    float4 y = ((const float4*)(o + (size_t)row * D_MODEL))[lane];
    x.x += y.x; x.y += y.y; x.z += y.z; x.w += y.w;
    float s = x.x + x.y + x.z + x.w;
    #pragma unroll
    for (int off = 32; off > 0; off >>= 1) s += __shfl_xor(s, off);
    float mean = s * (1.0f / D_MODEL);
    float dx0 = x.x - mean, dx1 = x.y - mean, dx2 = x.z - mean, dx3 = x.w - mean;
    float sq = dx0 * dx0 + dx1 * dx1 + dx2 * dx2 + dx3 * dx3;
    #pragma unroll
    for (int off = 32; off > 0; off >>= 1) sq += __shfl_xor(sq, off);
    float inv = 1.0f / sqrtf(sq * (1.0f / D_MODEL) + 1e-5f);
    float4 wv = ((const float4*)w)[lane];
    float4 bv = ((const float4*)b)[lane];
    float4 r;
    r.x = dx0 * inv * wv.x + bv.x;
    r.y = dx1 * inv * wv.y + bv.y;
    r.z = dx2 * inv * wv.z + bv.z;
    r.w = dx3 * inv * wv.w + bv.w;
    ((float4*)(z + (size_t)row * D_MODEL))[lane] = r;
    bf16x4 rb = {(bf16_t)r.x, (bf16_t)r.y, (bf16_t)r.z, (bf16_t)r.w};
    *(bf16x4*)(zb + (size_t)row * D_MODEL + lane * 4) = rb;
}

// ---------------------------------------------------------------------------
// fp32 GEMM for small heads: Y[M,N] = act(X[M,K] @ W[N,K]^T + bias)
// ---------------------------------------------------------------------------
template <int ACT>
__global__ void gemm_bias_kernel(const float* __restrict__ X, const float* __restrict__ W,
                                 const float* __restrict__ bias, float* __restrict__ Y,
                                 int M, int N, int K) {
    __shared__ float Xs[64][17];
    __shared__ float Ws[64][17];
    int tid = threadIdx.x;
    int tx = tid & 15;
    int ty = tid >> 4;
    int row0 = blockIdx.y * 64;
    int col0 = blockIdx.x * 64;
    float acc[4][4] = {};
    int lr = tid >> 2;
    int lk = (tid & 3) * 4;
    for (int k0 = 0; k0 < K; k0 += 16) {
        float4 xv = *(const float4*)&X[(size_t)(row0 + lr) * K + k0 + lk];
        float4 wv = *(const float4*)&W[(size_t)(col0 + lr) * K + k0 + lk];
        Xs[lr][lk + 0] = xv.x; Xs[lr][lk + 1] = xv.y; Xs[lr][lk + 2] = xv.z; Xs[lr][lk + 3] = xv.w;
        Ws[lr][lk + 0] = wv.x; Ws[lr][lk + 1] = wv.y; Ws[lr][lk + 2] = wv.z; Ws[lr][lk + 3] = wv.w;
        __syncthreads();
        #pragma unroll
        for (int kk = 0; kk < 16; ++kk) {
            float a[4], bb[4];
            #pragma unroll
            for (int i = 0; i < 4; ++i) a[i] = Xs[ty * 4 + i][kk];
            #pragma unroll
            for (int j = 0; j < 4; ++j) bb[j] = Ws[tx * 4 + j][kk];
            #pragma unroll
            for (int i = 0; i < 4; ++i)
                #pragma unroll
                for (int j = 0; j < 4; ++j) acc[i][j] += a[i] * bb[j];
        }
        __syncthreads();
    }
    #pragma unroll
    for (int i = 0; i < 4; ++i) {
        int row = row0 + ty * 4 + i;
        #pragma unroll
        for (int j = 0; j < 4; ++j) {
            int col = col0 + tx * 4 + j;
            float v = acc[i][j] + bias[col];
            if (ACT == 1) v = fmaxf(v, 0.0f);
            Y[(size_t)row * N + col] = v;
        }
    }
}

__global__ void gather_last_kernel(const float* __restrict__ z, float* __restrict__ zlast) {
    int row = blockIdx.x;
    int tid = threadIdx.x;
    int b = row >> 4;
    int p = row & 15;
    int l = (TT - 1) * PP + p;
    zlast[(size_t)row * D_MODEL + tid] = z[((size_t)(b * LL + l)) * D_MODEL + tid];
}

__global__ void scatter_head_kernel(const float* __restrict__ pre, float* __restrict__ out,
                                    float lo, float hi) {
    int e = blockIdx.x * 256 + threadIdx.x;
    int ww = e & 31;
    int hh = (e >> 5) & 31;
    int c = (e >> 10) & 1;
    int b = e >> 11;
    int p = (hh >> 3) * 4 + (ww >> 3);
    int dd = c * 64 + (hh & 7) * 8 + (ww & 7);
    float v = pre[((size_t)(b * PP + p)) * DATA_DIM + dd];
    out[e] = fminf(fmaxf(v, lo), hi);
}

// ---------------------------------------------------------------------------
extern "C" void kernel_launch(void* const* d_in, const int* in_sizes, int n_in,
                              void* d_out, int out_size, void* d_ws, size_t ws_size,
                              hipStream_t stream) {
    const float* img        = (const float*)d_in[0];
    const float* acq        = (const float*)d_in[1];
    const float* nan_token  = (const float*)d_in[2];
    const float* pad_embed  = (const float*)d_in[3];
    const float* emb_w      = (const float*)d_in[4];
    const float* emb_b      = (const float*)d_in[5];
    const float* spatial    = (const float*)d_in[6];
    const float* t_w1       = (const float*)d_in[7];
    const float* t_b1       = (const float*)d_in[8];
    const float* t_w2       = (const float*)d_in[9];
    const float* t_b2       = (const float*)d_in[10];
    const float* t_w3       = (const float*)d_in[11];
    const float* t_b3       = (const float*)d_in[12];
    const float* in_proj_w  = (const float*)d_in[13];
    const float* in_proj_b  = (const float*)d_in[14];
    const float* out_proj_w = (const float*)d_in[15];
    const float* out_proj_b = (const float*)d_in[16];
    const float* lin1_w     = (const float*)d_in[17];
    const float* lin1_b     = (const float*)d_in[18];
    const float* lin2_w     = (const float*)d_in[19];
    const float* lin2_b     = (const float*)d_in[20];
    const float* norm1_w    = (const float*)d_in[21];
    const float* norm1_b    = (const float*)d_in[22];
    const float* norm2_w    = (const float*)d_in[23];
    const float* norm2_b    = (const float*)d_in[24];
    const float* mean_w1    = (const float*)d_in[25];
    const float* mean_b1    = (const float*)d_in[26];
    const float* mean_w2    = (const float*)d_in[27];
    const float* mean_b2    = (const float*)d_in[28];
    const float* lv_w1      = (const float*)d_in[29];
    const float* lv_b1      = (const float*)d_in[30];
    const float* lv_w2      = (const float*)d_in[31];
    const float* lv_b2      = (const float*)d_in[32];

    const int M = BB * LL;   // 4096 tokens

    // ---- workspace carve-up ----
    char* wsb = (char*)d_ws;
    float* z       = (float*)wsb;                    wsb += (size_t)M * D_MODEL * 4;   // 4 MB
    float* tmpf    = (float*)wsb;                    wsb += (size_t)M * D_MODEL * 4;   // 4 MB
    float* temb    = (float*)wsb;                    wsb += (size_t)BB * TT * D_MODEL * 4;
    float* zlast   = (float*)wsb;                    wsb += 64 * D_MODEL * 4;
    float* hhead   = (float*)wsb;                    wsb += 64 * DFF * 4;
    float* prehead = (float*)wsb;                    wsb += 64 * DATA_DIM * 4;
    float* kmaskf  = (float*)wsb;                    wsb += M * 4;
    int* framepad  = (int*)wsb;                      wsb += BB * TT * 4;
    int* masked    = (int*)wsb;                      wsb += M * 4;
    wsb = (char*)(((uintptr_t)wsb + 255) & ~(uintptr_t)255);
    bf16_t* zb     = (bf16_t*)wsb;                   wsb += (size_t)M * D_MODEL * 2;   // 2 MB
    bf16_t* Qb     = (bf16_t*)wsb;                   wsb += (size_t)M * D_MODEL * 2;
    bf16_t* Kb     = (bf16_t*)wsb;                   wsb += (size_t)M * D_MODEL * 2;
    bf16_t* VtG    = (bf16_t*)wsb;                   wsb += (size_t)M * D_MODEL * 2;
    bf16_t* attnb  = (bf16_t*)wsb;                   wsb += (size_t)M * D_MODEL * 2;
    bf16_t* ff1b   = (bf16_t*)wsb;                   wsb += (size_t)M * DFF * 2;       // 8 MB
    bf16_t* inb    = (bf16_t*)wsb;                   wsb += (size_t)NLAYERS * 768 * D_MODEL * 2;
    bf16_t* outb   = (bf16_t*)wsb;                   wsb += (size_t)NLAYERS * D_MODEL * D_MODEL * 2;
    bf16_t* l1b    = (bf16_t*)wsb;                   wsb += (size_t)NLAYERS * DFF * D_MODEL * 2;
    bf16_t* l2b    = (bf16_t*)wsb;                   wsb += (size_t)NLAYERS * D_MODEL * DFF * 2;

    float* outF = (float*)d_out;

    // ---- weight conversion (bf16) ----
    {
        int n1 = NLAYERS * 768 * D_MODEL;
        f2b_kernel<<<(n1 / 4 + 255) / 256, 256, 0, stream>>>(in_proj_w, inb, n1);
        int n2 = NLAYERS * D_MODEL * D_MODEL;
        f2b_kernel<<<(n2 / 4 + 255) / 256, 256, 0, stream>>>(out_proj_w, outb, n2);
        int n3 = NLAYERS * DFF * D_MODEL;
        f2b_kernel<<<(n3 / 4 + 255) / 256, 256, 0, stream>>>(lin1_w, l1b, n3);
        int n4 = NLAYERS * D_MODEL * DFF;
        f2b_kernel<<<(n4 / 4 + 255) / 256, 256, 0, stream>>>(lin2_w, l2b, n4);
    }

    // ---- prep + embed ----
    prep_frame_kernel<<<BB * TT, 256, 0, stream>>>(img, acq, t_w1, t_b1, t_w2, t_b2,
                                                   t_w3, t_b3, temb, framepad);
    embed_kernel<<<BB * TT * PP, 256, 0, stream>>>(img, nan_token, pad_embed, emb_w, emb_b,
                                                   spatial, temb, framepad, z, zb, masked, kmaskf);

    // ---- transformer layers ----
    for (int l = 0; l < NLAYERS; ++l) {
        // qkv: (4096 x 768) -> Qb, Kb, VtG
        gemm_mfma<2, 0><<<dim3(768 / 64, M / 128), 256, 0, stream>>>(
            zb, inb + (size_t)l * 768 * D_MODEL, in_proj_b + (size_t)l * 768,
            nullptr, Qb, Kb, VtG, M, 768, D_MODEL);
        // attention -> attnb (bf16)
        attn_mfma<<<BB * NHEAD * (LL / 64), 256, 0, stream>>>(Qb, Kb, VtG, masked, kmaskf, attnb);
        // out_proj -> tmpf (fp32)
        gemm_mfma<0, 0><<<dim3(D_MODEL / 64, M / 128), 256, 0, stream>>>(
            attnb, outb + (size_t)l * D_MODEL * D_MODEL, out_proj_b + (size_t)l * D_MODEL,
            tmpf, nullptr, nullptr, nullptr, M, D_MODEL, D_MODEL);
        // z = LN(z + o)
        add_ln_kernel<<<M / 4, 256, 0, stream>>>(z, tmpf, norm1_w + l * D_MODEL,
                                                 norm1_b + l * D_MODEL, zb);
        // ff1 = relu(z @ lin1^T + b) -> ff1b (bf16)
        gemm_mfma<1, 1><<<dim3(DFF / 64, M / 128), 256, 0, stream>>>(
            zb, l1b + (size_t)l * DFF * D_MODEL, lin1_b + (size_t)l * DFF,
            ff1b, nullptr, nullptr, nullptr, M, DFF, D_MODEL);
        // ff2 -> tmpf (fp32)
        gemm_mfma<0, 0><<<dim3(D_MODEL / 64, M / 128), 256, 0, stream>>>(
            ff1b, l2b + (size_t)l * D_MODEL * DFF, lin2_b + (size_t)l * D_MODEL,
            tmpf, nullptr, nullptr, nullptr, M, D_MODEL, DFF);
        // z = LN(z + ff)
        add_ln_kernel<<<M / 4, 256, 0, stream>>>(z, tmpf, norm2_w + l * D_MODEL,
                                                 norm2_b + l * D_MODEL, zb);
    }

    // ---- heads on last frame only (64 rows, fp32) ----
    gather_last_kernel<<<64, 256, 0, stream>>>(z, zlast);

    gemm_bias_kernel<1><<<dim3(DFF / 64, 1), 256, 0, stream>>>(
        zlast, mean_w1, mean_b1, hhead, 64, DFF, D_MODEL);
    gemm_bias_kernel<0><<<dim3(DATA_DIM / 64, 1), 256, 0, stream>>>(
        hhead, mean_w2, mean_b2, prehead, 64, DATA_DIM, DFF);
    scatter_head_kernel<<<32, 256, 0, stream>>>(prehead, outF, -10.0f, 10.0f);

    gemm_bias_kernel<1><<<dim3(DFF / 64, 1), 256, 0, stream>>>(
        zlast, lv_w1, lv_b1, hhead, 64, DFF, D_MODEL);
    gemm_bias_kernel<0><<<dim3(DATA_DIM / 64, 1), 256, 0, stream>>>(
        hhead, lv_w2, lv_b2, prehead, 64, DATA_DIM, DFF);
    scatter_head_kernel<<<32, 256, 0, stream>>>(prehead, outF + 8192, -10.0f, 5.0f);
}

// Round 3
// 672.368 us; speedup vs baseline: 3.4068x; 1.2234x over previous
//
#include <hip/hip_runtime.h>
#include <hip/hip_bf16.h>

#define D_MODEL 256
#define NHEAD 8
#define DH 32
#define NLAYERS 4
#define DFF 1024
#define CC 2
#define DATA_DIM 128
#define PP 16
#define TT 64
#define BB 4
#define LL 1024
#define NEGV -1000000.0f

typedef __bf16 bf16_t;
typedef __bf16 bf16x8 __attribute__((ext_vector_type(8)));
typedef __bf16 bf16x4 __attribute__((ext_vector_type(4)));
typedef float v4f __attribute__((ext_vector_type(4)));

__device__ __forceinline__ bool my_isnan(float v) {
    unsigned u = __float_as_uint(v);
    return (u & 0x7fffffffu) > 0x7f800000u;
}

// ---------------------------------------------------------------------------
// Combined fp32 -> bf16 conversion for all 4 weight groups (1 dispatch)
// ---------------------------------------------------------------------------
__global__ void f2b_all_kernel(const float* __restrict__ s0, bf16_t* __restrict__ d0, int n0,
                               const float* __restrict__ s1, bf16_t* __restrict__ d1, int n1,
                               const float* __restrict__ s2, bf16_t* __restrict__ d2, int n2,
                               const float* __restrict__ s3, bf16_t* __restrict__ d3, int n3) {
    int i = (blockIdx.x * 256 + threadIdx.x) * 4;
    const float* s;
    bf16_t* d;
    if (i < n0) { s = s0; d = d0; }
    else if ((i -= n0) < n1) { s = s1; d = d1; }
    else if ((i -= n1) < n2) { s = s2; d = d2; }
    else if ((i -= n2) < n3) { s = s3; d = d3; }
    else return;
    float4 v = *(const float4*)(s + i);
    bf16x4 o = {(bf16_t)v.x, (bf16_t)v.y, (bf16_t)v.z, (bf16_t)v.w};
    *(bf16x4*)(d + i) = o;
}

// ---------------------------------------------------------------------------
// Prep: frame_pad detection + temporal embedding MLP (1 -> 64 -> 128 -> 256)
// ---------------------------------------------------------------------------
__global__ void prep_frame_kernel(const float* __restrict__ img,
                                  const float* __restrict__ acq,
                                  const float* __restrict__ t_w1, const float* __restrict__ t_b1,
                                  const float* __restrict__ t_w2, const float* __restrict__ t_b2,
                                  const float* __restrict__ t_w3, const float* __restrict__ t_b3,
                                  float* __restrict__ temb, int* __restrict__ framepad) {
    int f = blockIdx.x;
    int tid = threadIdx.x;
    __shared__ float h1[64];
    __shared__ float h2[128];
    __shared__ int sAll;
    if (tid == 0) sAll = 1;
    __syncthreads();
    const float* fr = img + (size_t)f * (CC * 32 * 32);
    bool allpad = true;
    #pragma unroll
    for (int i = 0; i < 8; ++i) {
        float v = fr[tid + i * 256];
        allpad = allpad && (v == -9999.0f);
    }
    if (!allpad) sAll = 0;
    __syncthreads();
    if (tid == 0) framepad[f] = sAll;

    float t_in = acq[f];
    if (my_isnan(t_in)) t_in = 0.0f;
    if (tid < 64) h1[tid] = fmaxf(t_w1[tid] * t_in + t_b1[tid], 0.0f);
    __syncthreads();
    if (tid < 128) {
        float a = t_b2[tid];
        #pragma unroll 8
        for (int j = 0; j < 64; ++j) a += t_w2[tid * 64 + j] * h1[j];
        h2[tid] = fmaxf(a, 0.0f);
    }
    __syncthreads();
    {
        float a = t_b3[tid];
        #pragma unroll 8
        for (int j = 0; j < 128; ++j) a += t_w3[tid * 128 + j] * h2[j];
        temb[(size_t)f * D_MODEL + tid] = a;
    }
}

// ---------------------------------------------------------------------------
// Embed: patchify + NaN/clip + linear embed + pos + temb + pad_embed
// ---------------------------------------------------------------------------
__global__ void embed_kernel(const float* __restrict__ img,
                             const float* __restrict__ nan_token,
                             const float* __restrict__ pad_embed,
                             const float* __restrict__ emb_w, const float* __restrict__ emb_b,
                             const float* __restrict__ spatial_pos,
                             const float* __restrict__ temb,
                             const int* __restrict__ framepad,
                             float* __restrict__ z, bf16_t* __restrict__ zb,
                             int* __restrict__ masked_rows, float* __restrict__ kmaskf) {
    int token = blockIdx.x;
    int b = token / (TT * PP);
    int rem = token % (TT * PP);
    int t = rem / PP;
    int p = rem % PP;
    int tid = threadIdx.x;
    __shared__ float xs[DATA_DIM];
    __shared__ int anyvalid;
    if (tid == 0) anyvalid = 0;
    __syncthreads();
    if (tid < DATA_DIM) {
        int c = tid >> 6;
        int pr = (tid >> 3) & 7;
        int pc = tid & 7;
        int hh = (p >> 2) * 8 + pr;
        int ww = (p & 3) * 8 + pc;
        float v = img[(((size_t)(b * TT + t) * CC + c) * 32 + hh) * 32 + ww];
        if (my_isnan(v)) {
            v = fminf(fmaxf(nan_token[c], -10.0f), 10.0f);
        } else {
            anyvalid = 1;
        }
        v = fminf(fmaxf(v, -10.0f), 10.0f);
        xs[tid] = v;
    }
    __syncthreads();
    int fp = framepad[b * TT + t];
    int l = t * PP + p;
    float zv;
    if (fp) {
        zv = pad_embed[tid];
    } else {
        float acc = emb_b[tid] + spatial_pos[p * D_MODEL + tid]
                  + temb[(size_t)(b * TT + t) * D_MODEL + tid];
        #pragma unroll 8
        for (int j = 0; j < DATA_DIM; ++j) acc += xs[j] * emb_w[tid * DATA_DIM + j];
        zv = acc;
    }
    size_t idx = ((size_t)(b * LL + l)) * D_MODEL + tid;
    z[idx] = zv;
    zb[idx] = (bf16_t)zv;
    if (tid == 0) {
        int sn = (anyvalid == 0) ? 1 : 0;
        masked_rows[b * LL + l] = sn | fp;
        kmaskf[b * LL + l] = fp ? NEGV : 0.0f;
    }
}

// ---------------------------------------------------------------------------
// MFMA GEMM: Y[M,N] = act(Xbf16[M,K] @ Wbf16[N,K]^T + bias[N])
// BM=128, BN=64, BK=32, 256 threads (4 waves).
// MODE 0: fp32 out; 1: bf16 out; 2: qkv split (Q/K row-major bf16, V transposed)
// ---------------------------------------------------------------------------
template <int MODE, int RELU>
__global__ __launch_bounds__(256) void gemm_mfma(
    const bf16_t* __restrict__ X, const bf16_t* __restrict__ W,
    const float* __restrict__ bias, void* __restrict__ Yv,
    bf16_t* __restrict__ Qb, bf16_t* __restrict__ Kb, bf16_t* __restrict__ Vt,
    int M, int N, int K) {
    __shared__ __align__(16) bf16_t Xs[128 * 32];
    __shared__ __align__(16) bf16_t Ws[64 * 32];
    int tid = threadIdx.x;
    int wave = tid >> 6, lane = tid & 63;
    int quad = lane >> 4, l16 = lane & 15;
    int m0 = blockIdx.y * 128, n0 = blockIdx.x * 64;

    v4f acc[2][4];
    #pragma unroll
    for (int i = 0; i < 2; ++i)
        #pragma unroll
        for (int j = 0; j < 4; ++j) acc[i][j] = (v4f){0.f, 0.f, 0.f, 0.f};

    int sr = tid >> 2, ss = tid & 3;
    for (int k0 = 0; k0 < K; k0 += 32) {
        uint4 a0 = *(const uint4*)(X + (size_t)(m0 + sr) * K + k0 + ss * 8);
        uint4 a1 = *(const uint4*)(X + (size_t)(m0 + 64 + sr) * K + k0 + ss * 8);
        uint4 b0 = *(const uint4*)(W + (size_t)(n0 + sr) * K + k0 + ss * 8);
        *(uint4*)(Xs + sr * 32 + ss * 8) = a0;
        *(uint4*)(Xs + (64 + sr) * 32 + ss * 8) = a1;
        *(uint4*)(Ws + sr * 32 + ss * 8) = b0;
        __syncthreads();
        bf16x8 af0 = *(const bf16x8*)(Xs + (wave * 32 + l16) * 32 + quad * 8);
        bf16x8 af1 = *(const bf16x8*)(Xs + (wave * 32 + 16 + l16) * 32 + quad * 8);
        #pragma unroll
        for (int nt = 0; nt < 4; ++nt) {
            bf16x8 bfr = *(const bf16x8*)(Ws + (nt * 16 + l16) * 32 + quad * 8);
            acc[0][nt] = __builtin_amdgcn_mfma_f32_16x16x32_bf16(af0, bfr, acc[0][nt], 0, 0, 0);
            acc[1][nt] = __builtin_amdgcn_mfma_f32_16x16x32_bf16(af1, bfr, acc[1][nt], 0, 0, 0);
        }
        __syncthreads();
    }

    #pragma unroll
    for (int mt = 0; mt < 2; ++mt) {
        #pragma unroll
        for (int nt = 0; nt < 4; ++nt) {
            int col = n0 + nt * 16 + l16;
            float bv = bias[col];
            #pragma unroll
            for (int reg = 0; reg < 4; ++reg) {
                int row = m0 + wave * 32 + mt * 16 + quad * 4 + reg;
                float v = acc[mt][nt][reg] + bv;
                if (RELU) v = fmaxf(v, 0.0f);
                if (MODE == 0) {
                    ((float*)Yv)[(size_t)row * N + col] = v;
                } else if (MODE == 1) {
                    ((bf16_t*)Yv)[(size_t)row * N + col] = (bf16_t)v;
                } else {
                    if (col < 256) {
                        Qb[(size_t)row * 256 + col] = (bf16_t)v;
                    } else if (col < 512) {
                        Kb[(size_t)row * 256 + (col - 256)] = (bf16_t)v;
                    } else {
                        int c = col - 512;
                        int h = c >> 5, d = c & 31;
                        int b = row >> 10, l = row & 1023;
                        Vt[(((size_t)(b * NHEAD + h)) * DH + d) * LL + l] = (bf16_t)v;
                    }
                }
            }
        }
    }
}

// ---------------------------------------------------------------------------
// Flash attention, bf16 MFMA. Block = (b, h, 64-row q-tile); wave = 16 q-rows.
// ---------------------------------------------------------------------------
__global__ __launch_bounds__(256) void attn_mfma(
    const bf16_t* __restrict__ Qb, const bf16_t* __restrict__ Kb,
    const bf16_t* __restrict__ Vt,
    const int* __restrict__ masked_rows, const float* __restrict__ kmaskf,
    bf16_t* __restrict__ Ob) {
    __shared__ __align__(16) bf16_t Ks[64 * 40];
    __shared__ __align__(16) bf16_t Vs[32 * 72];
    __shared__ __align__(16) bf16_t Ps[4 * 16 * 72];

    int tid = threadIdx.x;
    int wave = tid >> 6, lane = tid & 63;
    int quad = lane >> 4, l16 = lane & 15;
    int bid = blockIdx.x;
    int qt = bid & 15, h = (bid >> 4) & 7, b = bid >> 7;
    int q0 = qt * 64 + wave * 16;
    const float scale = 0.17677669529663687f;

    bf16x8 qf = *(const bf16x8*)(Qb + ((size_t)(b * LL) + q0 + l16) * 256 + h * DH + quad * 8);

    int mq[4];
    #pragma unroll
    for (int reg = 0; reg < 4; ++reg) mq[reg] = masked_rows[b * LL + q0 + quad * 4 + reg];

    float mrun[4], lrun[4];
    v4f oacc[2];
    #pragma unroll
    for (int reg = 0; reg < 4; ++reg) { mrun[reg] = -3.0e38f; lrun[reg] = 0.0f; }
    oacc[0] = (v4f){0.f, 0.f, 0.f, 0.f};
    oacc[1] = (v4f){0.f, 0.f, 0.f, 0.f};

    bf16_t* Pw = Ps + wave * 16 * 72;
    int kr = tid >> 2, ks = tid & 3;
    int vd = tid >> 3, vs = tid & 7;

    for (int c = 0; c < 16; ++c) {
        int k0 = c * 64;
        *(uint4*)(Ks + kr * 40 + ks * 8) =
            *(const uint4*)(Kb + ((size_t)(b * LL) + k0 + kr) * 256 + h * DH + ks * 8);
        *(uint4*)(Vs + vd * 72 + vs * 8) =
            *(const uint4*)(Vt + (((size_t)(b * NHEAD + h)) * DH + vd) * LL + k0 + vs * 8);
        __syncthreads();

        v4f sf[4];
        #pragma unroll
        for (int nt = 0; nt < 4; ++nt) {
            bf16x8 kf = *(const bf16x8*)(Ks + (nt * 16 + l16) * 40 + quad * 8);
            v4f zf = (v4f){0.f, 0.f, 0.f, 0.f};
            sf[nt] = __builtin_amdgcn_mfma_f32_16x16x32_bf16(qf, kf, zf, 0, 0, 0);
        }

        float sv[4][4];
        #pragma unroll
        for (int nt = 0; nt < 4; ++nt) {
            int kg = k0 + nt * 16 + l16;
            float km = kmaskf[b * LL + kg];
            #pragma unroll
            for (int reg = 0; reg < 4; ++reg) {
                float v = sf[nt][reg] * scale + km;
                if (mq[reg] && (q0 + quad * 4 + reg != kg)) v += NEGV;
                sv[nt][reg] = v;
            }
        }

        float tm[4];
        #pragma unroll
        for (int reg = 0; reg < 4; ++reg) {
            float m = sv[0][reg];
            m = fmaxf(m, sv[1][reg]); m = fmaxf(m, sv[2][reg]); m = fmaxf(m, sv[3][reg]);
            tm[reg] = m;
        }
        #pragma unroll
        for (int off = 1; off < 16; off <<= 1)
            #pragma unroll
            for (int reg = 0; reg < 4; ++reg) tm[reg] = fmaxf(tm[reg], __shfl_xor(tm[reg], off));

        float alpha[4], psum[4];
        #pragma unroll
        for (int reg = 0; reg < 4; ++reg) {
            float mnew = fmaxf(mrun[reg], tm[reg]);
            alpha[reg] = __expf(mrun[reg] - mnew);
            mrun[reg] = mnew;
            float ps = 0.0f;
            #pragma unroll
            for (int nt = 0; nt < 4; ++nt) {
                float p = __expf(sv[nt][reg] - mnew);
                sv[nt][reg] = p;
                ps += p;
            }
            psum[reg] = ps;
        }
        #pragma unroll
        for (int off = 1; off < 16; off <<= 1)
            #pragma unroll
            for (int reg = 0; reg < 4; ++reg) psum[reg] += __shfl_xor(psum[reg], off);
        #pragma unroll
        for (int reg = 0; reg < 4; ++reg) {
            lrun[reg] = lrun[reg] * alpha[reg] + psum[reg];
            oacc[0][reg] *= alpha[reg];
            oacc[1][reg] *= alpha[reg];
        }

        #pragma unroll
        for (int nt = 0; nt < 4; ++nt)
            #pragma unroll
            for (int reg = 0; reg < 4; ++reg)
                Pw[(quad * 4 + reg) * 72 + nt * 16 + l16] = (bf16_t)sv[nt][reg];

        #pragma unroll
        for (int kt = 0; kt < 2; ++kt) {
            bf16x8 pf = *(const bf16x8*)(Pw + l16 * 72 + kt * 32 + quad * 8);
            #pragma unroll
            for (int nt2 = 0; nt2 < 2; ++nt2) {
                bf16x8 vf = *(const bf16x8*)(Vs + (nt2 * 16 + l16) * 72 + kt * 32 + quad * 8);
                oacc[nt2] = __builtin_amdgcn_mfma_f32_16x16x32_bf16(pf, vf, oacc[nt2], 0, 0, 0);
            }
        }
        __syncthreads();
    }

    #pragma unroll
    for (int nt2 = 0; nt2 < 2; ++nt2)
        #pragma unroll
        for (int reg = 0; reg < 4; ++reg) {
            size_t row = (size_t)(b * LL) + q0 + quad * 4 + reg;
            Ob[row * 256 + h * DH + nt2 * 16 + l16] = (bf16_t)(oacc[nt2][reg] / lrun[reg]);
        }
}

// ---------------------------------------------------------------------------
// Residual add + LayerNorm, wave-per-row. Writes z fp32 + zb bf16.
// ---------------------------------------------------------------------------
__global__ __launch_bounds__(256) void add_ln_kernel(
    float* __restrict__ z, const float* __restrict__ o,
    const float* __restrict__ w, const float* __restrict__ b,
    bf16_t* __restrict__ zb) {
    int wave = threadIdx.x >> 6, lane = threadIdx.x & 63;
    int row = blockIdx.x * 4 + wave;
    float4 x = ((const float4*)(z + (size_t)row * D_MODEL))[lane];
    float4 y = ((const float4*)(o + (size_t)row * D_MODEL))[lane];
    x.x += y.x; x.y += y.y; x.z += y.z; x.w += y.w;
    float s = x.x + x.y + x.z + x.w;
    #pragma unroll
    for (int off = 32; off > 0; off >>= 1) s += __shfl_xor(s, off);
    float mean = s * (1.0f / D_MODEL);
    float dx0 = x.x - mean, dx1 = x.y - mean, dx2 = x.z - mean, dx3 = x.w - mean;
    float sq = dx0 * dx0 + dx1 * dx1 + dx2 * dx2 + dx3 * dx3;
    #pragma unroll
    for (int off = 32; off > 0; off >>= 1) sq += __shfl_xor(sq, off);
    float inv = 1.0f / sqrtf(sq * (1.0f / D_MODEL) + 1e-5f);
    float4 wv = ((const float4*)w)[lane];
    float4 bv = ((const float4*)b)[lane];
    float4 r;
    r.x = dx0 * inv * wv.x + bv.x;
    r.y = dx1 * inv * wv.y + bv.y;
    r.z = dx2 * inv * wv.z + bv.z;
    r.w = dx3 * inv * wv.w + bv.w;
    ((float4*)(z + (size_t)row * D_MODEL))[lane] = r;
    bf16x4 rb = {(bf16_t)r.x, (bf16_t)r.y, (bf16_t)r.z, (bf16_t)r.w};
    *(bf16x4*)(zb + (size_t)row * D_MODEL + lane * 4) = rb;
}

// ---------------------------------------------------------------------------
// Fused head: gather last-frame row -> relu MLP (256->1024->128) -> clip ->
// unpatch scatter. Block = (head, row): blockIdx.x = head*64 + (b*16+p).
// 128 blocks x 256 threads; weight reads consume full 64B lines per thread.
// ---------------------------------------------------------------------------
__global__ __launch_bounds__(256) void head_kernel(
    const float* __restrict__ z,
    const float* __restrict__ mean_w1, const float* __restrict__ mean_b1,
    const float* __restrict__ mean_w2, const float* __restrict__ mean_b2,
    const float* __restrict__ lv_w1, const float* __restrict__ lv_b1,
    const float* __restrict__ lv_w2, const float* __restrict__ lv_b2,
    float* __restrict__ out) {
    __shared__ __align__(16) float zrow[256];
    __shared__ __align__(16) float hrow[1024];
    int tid = threadIdx.x;
    int head = blockIdx.x >> 6;
    int row = blockIdx.x & 63;
    int b = row >> 4, p = row & 15;
    const float* W1 = head ? lv_w1 : mean_w1;
    const float* B1 = head ? lv_b1 : mean_b1;
    const float* W2 = head ? lv_w2 : mean_w2;
    const float* B2 = head ? lv_b2 : mean_b2;
    float hi = head ? 5.0f : 10.0f;

    zrow[tid] = z[((size_t)(b * LL + (TT - 1) * PP + p)) * D_MODEL + tid];
    __syncthreads();

    // stage 1: h[o] for o = tid*4..tid*4+3, K=256 in 16-float chunks
    {
        float acc[4];
        #pragma unroll
        for (int j = 0; j < 4; ++j) acc[j] = B1[tid * 4 + j];
        for (int kc = 0; kc < 16; ++kc) {
            float4 z0 = *(const float4*)(zrow + kc * 16);
            float4 z1 = *(const float4*)(zrow + kc * 16 + 4);
            float4 z2 = *(const float4*)(zrow + kc * 16 + 8);
            float4 z3 = *(const float4*)(zrow + kc * 16 + 12);
            #pragma unroll
            for (int j = 0; j < 4; ++j) {
                const float4* wr = (const float4*)(W1 + (size_t)(tid * 4 + j) * 256 + kc * 16);
                float4 w0 = wr[0], w1 = wr[1], w2 = wr[2], w3 = wr[3];
                acc[j] += w0.x * z0.x + w0.y * z0.y + w0.z * z0.z + w0.w * z0.w
                        + w1.x * z1.x + w1.y * z1.y + w1.z * z1.z + w1.w * z1.w
                        + w2.x * z2.x + w2.y * z2.y + w2.z * z2.z + w2.w * z2.w
                        + w3.x * z3.x + w3.y * z3.y + w3.z * z3.z + w3.w * z3.w;
            }
        }
        #pragma unroll
        for (int j = 0; j < 4; ++j) hrow[tid * 4 + j] = fmaxf(acc[j], 0.0f);
    }
    __syncthreads();

    // stage 2: 128 outputs, K=1024; threads 0..127 active, one output each
    if (tid < DATA_DIM) {
        float acc = B2[tid];
        for (int kc = 0; kc < 64; ++kc) {
            float4 h0 = *(const float4*)(hrow + kc * 16);
            float4 h1 = *(const float4*)(hrow + kc * 16 + 4);
            float4 h2 = *(const float4*)(hrow + kc * 16 + 8);
            float4 h3 = *(const float4*)(hrow + kc * 16 + 12);
            const float4* wr = (const float4*)(W2 + (size_t)tid * 1024 + kc * 16);
            float4 w0 = wr[0], w1 = wr[1], w2 = wr[2], w3 = wr[3];
            acc += w0.x * h0.x + w0.y * h0.y + w0.z * h0.z + w0.w * h0.w
                 + w1.x * h1.x + w1.y * h1.y + w1.z * h1.z + w1.w * h1.w
                 + w2.x * h2.x + w2.y * h2.y + w2.z * h2.z + w2.w * h2.w
                 + w3.x * h3.x + w3.y * h3.y + w3.z * h3.z + w3.w * h3.w;
        }
        float v = fminf(fmaxf(acc, -10.0f), hi);
        // unpatch scatter: dd = tid -> (c, pr, pc); p -> (ph, pw)
        int c = tid >> 6;
        int pr = (tid >> 3) & 7, pc = tid & 7;
        int hh = (p >> 2) * 8 + pr, ww = (p & 3) * 8 + pc;
        out[(size_t)head * 8192 + ((size_t)(b * CC + c)) * 1024 + hh * 32 + ww] = v;
    }
}

// ---------------------------------------------------------------------------
extern "C" void kernel_launch(void* const* d_in, const int* in_sizes, int n_in,
                              void* d_out, int out_size, void* d_ws, size_t ws_size,
                              hipStream_t stream) {
    const float* img        = (const float*)d_in[0];
    const float* acq        = (const float*)d_in[1];
    const float* nan_token  = (const float*)d_in[2];
    const float* pad_embed  = (const float*)d_in[3];
    const float* emb_w      = (const float*)d_in[4];
    const float* emb_b      = (const float*)d_in[5];
    const float* spatial    = (const float*)d_in[6];
    const float* t_w1       = (const float*)d_in[7];
    const float* t_b1       = (const float*)d_in[8];
    const float* t_w2       = (const float*)d_in[9];
    const float* t_b2       = (const float*)d_in[10];
    const float* t_w3       = (const float*)d_in[11];
    const float* t_b3       = (const float*)d_in[12];
    const float* in_proj_w  = (const float*)d_in[13];
    const float* in_proj_b  = (const float*)d_in[14];
    const float* out_proj_w = (const float*)d_in[15];
    const float* out_proj_b = (const float*)d_in[16];
    const float* lin1_w     = (const float*)d_in[17];
    const float* lin1_b     = (const float*)d_in[18];
    const float* lin2_w     = (const float*)d_in[19];
    const float* lin2_b     = (const float*)d_in[20];
    const float* norm1_w    = (const float*)d_in[21];
    const float* norm1_b    = (const float*)d_in[22];
    const float* norm2_w    = (const float*)d_in[23];
    const float* norm2_b    = (const float*)d_in[24];
    const float* mean_w1    = (const float*)d_in[25];
    const float* mean_b1    = (const float*)d_in[26];
    const float* mean_w2    = (const float*)d_in[27];
    const float* mean_b2    = (const float*)d_in[28];
    const float* lv_w1      = (const float*)d_in[29];
    const float* lv_b1      = (const float*)d_in[30];
    const float* lv_w2      = (const float*)d_in[31];
    const float* lv_b2      = (const float*)d_in[32];

    const int M = BB * LL;   // 4096 tokens

    // ---- workspace carve-up ----
    char* wsb = (char*)d_ws;
    float* z       = (float*)wsb;                    wsb += (size_t)M * D_MODEL * 4;
    float* tmpf    = (float*)wsb;                    wsb += (size_t)M * D_MODEL * 4;
    float* temb    = (float*)wsb;                    wsb += (size_t)BB * TT * D_MODEL * 4;
    float* kmaskf  = (float*)wsb;                    wsb += M * 4;
    int* framepad  = (int*)wsb;                      wsb += BB * TT * 4;
    int* masked    = (int*)wsb;                      wsb += M * 4;
    wsb = (char*)(((uintptr_t)wsb + 255) & ~(uintptr_t)255);
    bf16_t* zb     = (bf16_t*)wsb;                   wsb += (size_t)M * D_MODEL * 2;
    bf16_t* Qb     = (bf16_t*)wsb;                   wsb += (size_t)M * D_MODEL * 2;
    bf16_t* Kb     = (bf16_t*)wsb;                   wsb += (size_t)M * D_MODEL * 2;
    bf16_t* VtG    = (bf16_t*)wsb;                   wsb += (size_t)M * D_MODEL * 2;
    bf16_t* attnb  = (bf16_t*)wsb;                   wsb += (size_t)M * D_MODEL * 2;
    bf16_t* ff1b   = (bf16_t*)wsb;                   wsb += (size_t)M * DFF * 2;
    bf16_t* inb    = (bf16_t*)wsb;                   wsb += (size_t)NLAYERS * 768 * D_MODEL * 2;
    bf16_t* outb   = (bf16_t*)wsb;                   wsb += (size_t)NLAYERS * D_MODEL * D_MODEL * 2;
    bf16_t* l1b    = (bf16_t*)wsb;                   wsb += (size_t)NLAYERS * DFF * D_MODEL * 2;
    bf16_t* l2b    = (bf16_t*)wsb;                   wsb += (size_t)NLAYERS * D_MODEL * DFF * 2;

    float* outF = (float*)d_out;

    // ---- weight conversion (1 dispatch) ----
    {
        int n1 = NLAYERS * 768 * D_MODEL;
        int n2 = NLAYERS * D_MODEL * D_MODEL;
        int n3 = NLAYERS * DFF * D_MODEL;
        int n4 = NLAYERS * D_MODEL * DFF;
        int tot = n1 + n2 + n3 + n4;
        f2b_all_kernel<<<(tot / 4 + 255) / 256, 256, 0, stream>>>(
            in_proj_w, inb, n1, out_proj_w, outb, n2, lin1_w, l1b, n3, lin2_w, l2b, n4);
    }

    // ---- prep + embed ----
    prep_frame_kernel<<<BB * TT, 256, 0, stream>>>(img, acq, t_w1, t_b1, t_w2, t_b2,
                                                   t_w3, t_b3, temb, framepad);
    embed_kernel<<<BB * TT * PP, 256, 0, stream>>>(img, nan_token, pad_embed, emb_w, emb_b,
                                                   spatial, temb, framepad, z, zb, masked, kmaskf);

    // ---- transformer layers ----
    for (int l = 0; l < NLAYERS; ++l) {
        gemm_mfma<2, 0><<<dim3(768 / 64, M / 128), 256, 0, stream>>>(
            zb, inb + (size_t)l * 768 * D_MODEL, in_proj_b + (size_t)l * 768,
            nullptr, Qb, Kb, VtG, M, 768, D_MODEL);
        attn_mfma<<<BB * NHEAD * (LL / 64), 256, 0, stream>>>(Qb, Kb, VtG, masked, kmaskf, attnb);
        gemm_mfma<0, 0><<<dim3(D_MODEL / 64, M / 128), 256, 0, stream>>>(
            attnb, outb + (size_t)l * D_MODEL * D_MODEL, out_proj_b + (size_t)l * D_MODEL,
            tmpf, nullptr, nullptr, nullptr, M, D_MODEL, D_MODEL);
        add_ln_kernel<<<M / 4, 256, 0, stream>>>(z, tmpf, norm1_w + l * D_MODEL,
                                                 norm1_b + l * D_MODEL, zb);
        gemm_mfma<1, 1><<<dim3(DFF / 64, M / 128), 256, 0, stream>>>(
            zb, l1b + (size_t)l * DFF * D_MODEL, lin1_b + (size_t)l * DFF,
            ff1b, nullptr, nullptr, nullptr, M, DFF, D_MODEL);
        gemm_mfma<0, 0><<<dim3(D_MODEL / 64, M / 128), 256, 0, stream>>>(
            ff1b, l2b + (size_t)l * D_MODEL * DFF, lin2_b + (size_t)l * D_MODEL,
            tmpf, nullptr, nullptr, nullptr, M, D_MODEL, DFF);
        add_ln_kernel<<<M / 4, 256, 0, stream>>>(z, tmpf, norm2_w + l * D_MODEL,
                                                 norm2_b + l * D_MODEL, zb);
    }

    // ---- fused heads (gather + MLP + clip + scatter), 1 dispatch ----
    head_kernel<<<128, 256, 0, stream>>>(z, mean_w1, mean_b1, mean_w2, mean_b2,
                                         lv_w1, lv_b1, lv_w2, lv_b2, outF);
}